// Round 3
// baseline (68.103 us; speedup 1.0000x reference)
//
#include <hip/hip_runtime.h>

#define NN 4096
#define TT 365
#define CC 32
#define WPB 4                 // waves per block = rows per block
#define BLOCK (WPB * 64)      // 256
#define GRID (NN / WPB)       // 1024

// Workspace layout (doubles):
// [0..TT)    cls sums (sum over n of -logp[n,t,y])
// [TT]       earliness sum (over all n,t)
// [TT+1        .. TT+1+CC)   A[c] = sum e
// [TT+1+CC     .. TT+1+2CC)  B[c] = sum e*tf
// [TT+1+2CC    .. TT+1+3CC)  D[c] = sum e*tf*tf
#define WS_DOUBLES (TT + 1 + 3 * CC)

__global__ __launch_bounds__(BLOCK) void stp_main(
    const float* __restrict__ logp,   // (N,T,C)
    const float* __restrict__ tl,     // (N,T) -- only column 0 read
    const int*  __restrict__ yt,      // (N,T) -- only column 0 read
    double* __restrict__ ws)
{
    __shared__ float  s_cls[WPB][TT + 3];   // per-wave row slice, no atomics
    __shared__ double s_red[WPB];

    const int tid  = threadIdx.x;
    const int wv   = tid >> 6;
    const int lane = tid & 63;
    const int n    = blockIdx.x * WPB + wv;

    for (int i = tid; i < WPB * (TT + 3); i += BLOCK)
        (&s_cls[0][0])[i] = 0.0f;
    __syncthreads();

    const size_t rowbase = (size_t)n * TT;
    const int   label = yt[rowbase];        // uniform per wave -> broadcast
    const float tf_f  = tl[rowbase];        // tl[n,0] = t_final (exact int)
    const int   tf    = (int)tf_f;

    // The label's float lives in 64B half h of each 128B cell. 4 lanes per
    // cell cover that half with 4x float4 -> granule fully consumed.
    const int  h     = label >> 4;
    const int  oc    = (label >> 2) & 3;    // owning lane within group of 4
    const int  comp  = label & 3;           // component within owner's float4
    const bool owner = (lane & 3) == oc;
    const int  cbase = lane >> 2;           // 0..15: cell offset within iter

    const float* rowp = logp + rowbase * CC + h * 16 + (lane & 3) * 4;

    double earl  = 0.0;
    double e_val = 0.0;
    bool   hit   = false;
    const float invT = 1.0f / 365.0f;

    #pragma unroll 4
    for (int k = 0; k < 23; ++k) {
        const int c = k * 16 + cbase;       // cell (= t) handled by this group
        if (c < TT) {
            const float4 v = *(const float4*)(rowp + (size_t)c * CC);
            if (owner) {
                const float lp = comp == 0 ? v.x : comp == 1 ? v.y
                               : comp == 2 ? v.z : v.w;
                s_cls[wv][c] = -lp;
                const float pc  = expf(lp);
                const float tlv = fmaxf(tf_f - (float)c, 0.0f);
                earl += (double)(pc * (1.0f - (float)c * invT)
                                    * (1.0f - tlv * invT));
                if (c == tf) { e_val = (double)pc; hit = true; }
            }
        }
    }

    // earliness: wave shuffle-reduce (f64)
    for (int off = 32; off > 0; off >>= 1)
        earl += __shfl_down(earl, off, 64);
    if (lane == 0) s_red[wv] = earl;

    // proximity moments: exactly one lane per wave hit c==tf
    if (hit) {
        const double tfd = (double)tf;
        atomicAdd(&ws[TT + 1 + label],          e_val);
        atomicAdd(&ws[TT + 1 + CC + label],     e_val * tfd);
        atomicAdd(&ws[TT + 1 + 2 * CC + label], e_val * tfd * tfd);
    }

    __syncthreads();

    // flush: sum the WPB per-wave row slices, one f64 atomic per t per block
    for (int i = tid; i < TT; i += BLOCK) {
        float s = 0.0f;
        #pragma unroll
        for (int w = 0; w < WPB; ++w) s += s_cls[w][i];
        atomicAdd(&ws[i], (double)s);
    }
    if (tid == 0) {
        double s = 0.0;
        #pragma unroll
        for (int w = 0; w < WPB; ++w) s += s_red[w];
        atomicAdd(&ws[TT], s);
    }
}

__global__ __launch_bounds__(BLOCK) void stp_finalize(
    const double* __restrict__ ws, float* __restrict__ out)
{
    __shared__ double s_scalar;
    const int tid = threadIdx.x;
    if (tid == 0) {
        double p = 0.0;
        #pragma unroll
        for (int c = 0; c < CC; ++c) {
            const double A = ws[TT + 1 + c];
            const double B = ws[TT + 1 + CC + c];
            const double D = ws[TT + 1 + 2 * CC + c];
            p += A * D - B * B;
        }
        p /= (365.0 * 365.0);
        const double e = ws[TT] / (double)NN;
        s_scalar = (1.0 / 3.0) * (e + p);
    }
    __syncthreads();
    for (int i = tid; i < TT; i += BLOCK) {
        const double cls = ws[i] / (double)NN;
        out[i] = (float)((1.0 / 3.0) * cls - s_scalar);
    }
}

extern "C" void kernel_launch(void* const* d_in, const int* in_sizes, int n_in,
                              void* d_out, int out_size, void* d_ws, size_t ws_size,
                              hipStream_t stream)
{
    const float* logp = (const float*)d_in[0];
    const float* tl   = (const float*)d_in[1];
    const int*   yt   = (const int*)d_in[2];
    float* out = (float*)d_out;
    double* ws = (double*)d_ws;

    hipMemsetAsync(ws, 0, WS_DOUBLES * sizeof(double), stream);
    stp_main<<<GRID, BLOCK, 0, stream>>>(logp, tl, yt, ws);
    stp_finalize<<<1, BLOCK, 0, stream>>>(ws, out);
}

// Round 4
// 58.593 us; speedup vs baseline: 1.1623x; 1.1623x over previous
//
#include <hip/hip_runtime.h>

#define NN 4096
#define TT 365
#define CC 32
#define RPB 8                  // rows per block
#define BLOCK 256              // 4 waves
#define GRID (NN / RPB)        // 512
#define F4_PER_ROW (TT * CC / 4)   // 2920

// Workspace layout (doubles):
// [0..TT)    cls sums (sum over n of -logp[n,t,y])
// [TT]       earliness sum (over all n,t)
// [TT+1        .. TT+1+CC)   A[c] = sum e
// [TT+1+CC     .. TT+1+2CC)  B[c] = sum e*tf
// [TT+1+2CC    .. TT+1+3CC)  D[c] = sum e*tf*tf
#define WS_DOUBLES (TT + 1 + 3 * CC)

__global__ __launch_bounds__(BLOCK) void stp_main(
    const float* __restrict__ logp,   // (N,T,C)
    const float* __restrict__ tl,     // (N,T) -- only column 0 read
    const int*  __restrict__ yt,      // (N,T) -- only column 0 read
    double* __restrict__ ws)
{
    __shared__ float  s_cls[8][TT + 7];   // [chunk j][t]; bijective stores, no init
    __shared__ double s_red[BLOCK / 64];

    const int tid = threadIdx.x;
    const int n0  = blockIdx.x * RPB;

    // Block-uniform per-row params (SGPRs after readfirstlane-style uniformity)
    int   lab[RPB], j0[RPB], comp[RPB];
    float tff[RPB];
    const float* rowp[RPB];
    #pragma unroll
    for (int r = 0; r < RPB; ++r) {
        const size_t rb = (size_t)(n0 + r) * TT;
        lab[r]  = yt[rb];
        tff[r]  = tl[rb];              // tl[n,0] = lengths-1 = t_final (exact)
        j0[r]   = lab[r] >> 2;         // owning float4 chunk within 32-float cell
        comp[r] = lab[r] & 3;          // component within that float4
        rowp[r] = logp + rb * CC;
    }

    double earl = 0.0;
    const float invT = 1.0f / 365.0f;

    for (int i = tid; i < F4_PER_ROW; i += BLOCK) {
        // ---- batch: 8 independent coalesced loads, all in flight ----
        float4 v[RPB];
        #pragma unroll
        for (int r = 0; r < RPB; ++r)
            v[r] = *(const float4*)(rowp[r] + (size_t)i * 4);

        const int   j  = i & 7;
        const int   t  = i >> 3;
        const float tF = (float)t;
        const float wt = 1.0f - tF * invT;

        float acc = 0.0f;                 // sum over matching rows of -lp
        #pragma unroll
        for (int r = 0; r < RPB; ++r) {
            if (j == j0[r]) {
                const int   c  = comp[r];
                const float lp = c == 0 ? v[r].x : c == 1 ? v[r].y
                               : c == 2 ? v[r].z : v[r].w;
                acc -= lp;
                const float pc  = expf(lp);
                const float tlv = fmaxf(tff[r] - tF, 0.0f);
                earl += (double)(pc * wt * (1.0f - tlv * invT));
                if (tF == tff[r]) {       // stopping-time cell (once per row)
                    const double e   = (double)pc;
                    const double tfd = (double)tF;
                    atomicAdd(&ws[TT + 1 + lab[r]],          e);
                    atomicAdd(&ws[TT + 1 + CC + lab[r]],     e * tfd);
                    atomicAdd(&ws[TT + 1 + 2 * CC + lab[r]], e * tfd * tfd);
                }
            }
        }
        s_cls[j][t] = acc;               // plain store: unique (j,t) per thread
    }

    // earliness: wave shuffle-reduce (f64) -> cross-wave LDS -> one atomic
    for (int off = 32; off > 0; off >>= 1)
        earl += __shfl_down(earl, off, 64);
    if ((tid & 63) == 0) s_red[tid >> 6] = earl;
    __syncthreads();
    if (tid == 0) {
        double s = 0.0;
        #pragma unroll
        for (int w = 0; w < BLOCK / 64; ++w) s += s_red[w];
        atomicAdd(&ws[TT], s);
    }

    // flush cls partials: sum the 8 chunk slices, one f64 atomic per t
    for (int i = tid; i < TT; i += BLOCK) {
        float s = 0.0f;
        #pragma unroll
        for (int jj = 0; jj < 8; ++jj) s += s_cls[jj][i];
        atomicAdd(&ws[i], (double)s);
    }
}

__global__ __launch_bounds__(BLOCK) void stp_finalize(
    const double* __restrict__ ws, float* __restrict__ out)
{
    __shared__ double s_scalar;
    const int tid = threadIdx.x;
    if (tid == 0) {
        double p = 0.0;
        #pragma unroll
        for (int c = 0; c < CC; ++c) {
            const double A = ws[TT + 1 + c];
            const double B = ws[TT + 1 + CC + c];
            const double D = ws[TT + 1 + 2 * CC + c];
            p += A * D - B * B;
        }
        p /= (365.0 * 365.0);
        const double e = ws[TT] / (double)NN;
        s_scalar = (1.0 / 3.0) * (e + p);
    }
    __syncthreads();
    for (int i = tid; i < TT; i += BLOCK) {
        const double cls = ws[i] / (double)NN;
        out[i] = (float)((1.0 / 3.0) * cls - s_scalar);
    }
}

extern "C" void kernel_launch(void* const* d_in, const int* in_sizes, int n_in,
                              void* d_out, int out_size, void* d_ws, size_t ws_size,
                              hipStream_t stream)
{
    const float* logp = (const float*)d_in[0];
    const float* tl   = (const float*)d_in[1];
    const int*   yt   = (const int*)d_in[2];
    float* out = (float*)d_out;
    double* ws = (double*)d_ws;

    hipMemsetAsync(ws, 0, WS_DOUBLES * sizeof(double), stream);
    stp_main<<<GRID, BLOCK, 0, stream>>>(logp, tl, yt, ws);
    stp_finalize<<<1, BLOCK, 0, stream>>>(ws, out);
}